// Round 1
// baseline (261.288 us; speedup 1.0000x reference)
//
#include <hip/hip_runtime.h>

#define DIM 192
#define PLANE (DIM * DIM)              // 36864
#define VOL ((size_t)PLANE * DIM)      // 7077888
#define NTOT (2.0 * 7077888.0)         // 14155776 voxels

__device__ __forceinline__ float robustf(float x) {
    float ax = fabsf(x);
    // delta = 0.01
    return (ax <= 0.01f) ? (0.5f * x * x) : (0.01f * (ax - 0.005f));
}

__global__ __launch_bounds__(256)
void elastic_main(const float* __restrict__ df, double* __restrict__ acc) {
    const int tx = threadIdx.x;
    const int k = (blockIdx.x % 3) * 64 + (tx & 63);   // contiguous axis -> coalesced
    const int j = (blockIdx.x / 3) * 4 + (tx >> 6);
    const int i0 = blockIdx.y * 24;
    const int b = blockIdx.z;

    const float* __restrict__ u = df + (size_t)(b * 3 + 0) * VOL;
    const float* __restrict__ v = df + (size_t)(b * 3 + 1) * VOL;
    const float* __restrict__ w = df + (size_t)(b * 3 + 2) * VOL;

    const int jp = (j < DIM - 1) ? j + 1 : j;
    const int jm = (j > 0) ? j - 1 : j;
    const int kp = (k < DIM - 1) ? k + 1 : k;
    const int km = (k > 0) ? k - 1 : k;
    const float sy = ((jp - jm) == 2) ? 0.5f : 1.0f;
    const float sz = ((kp - km) == 2) ? 0.5f : 1.0f;

    float vsum = 0.0f;

    for (int ii = 0; ii < 24; ++ii) {
        const int i = i0 + ii;
        const int ip = (i < DIM - 1) ? i + 1 : i;
        const int im = (i > 0) ? i - 1 : i;
        const float sx = ((ip - im) == 2) ? 0.5f : 1.0f;

        const size_t rowC  = (size_t)i  * PLANE + (size_t)j  * DIM;
        const size_t rowXp = (size_t)ip * PLANE + (size_t)j  * DIM;
        const size_t rowXm = (size_t)im * PLANE + (size_t)j  * DIM;
        const size_t rowYp = (size_t)i  * PLANE + (size_t)jp * DIM;
        const size_t rowYm = (size_t)i  * PLANE + (size_t)jm * DIM;

        const float du_dx = (u[rowXp + k] - u[rowXm + k]) * sx;
        const float dv_dx = (v[rowXp + k] - v[rowXm + k]) * sx;
        const float dw_dx = (w[rowXp + k] - w[rowXm + k]) * sx;
        const float du_dy = (u[rowYp + k] - u[rowYm + k]) * sy;
        const float dv_dy = (v[rowYp + k] - v[rowYm + k]) * sy;
        const float dw_dy = (w[rowYp + k] - w[rowYm + k]) * sy;
        const float du_dz = (u[rowC + kp] - u[rowC + km]) * sz;
        const float dv_dz = (v[rowC + kp] - v[rowC + km]) * sz;
        const float dw_dz = (w[rowC + kp] - w[rowC + km]) * sz;

        const float E_xy = 0.5f * (du_dy + dv_dx);
        const float E_xz = 0.5f * (du_dz + dw_dx);
        const float E_yz = 0.5f * (dv_dz + dw_dy);
        const float tr   = du_dx + dv_dy + dw_dz;

        const float rtr = robustf(tr);
        const float rxx = robustf(du_dx), ryy = robustf(dv_dy), rzz = robustf(dw_dz);
        const float rxy = robustf(E_xy),  rxz = robustf(E_xz),  ryz = robustf(E_yz);

        // 0.5*LAMBDA*rtr^2 + MU*(rxx^2+ryy^2+rzz^2 + 2*(rxy^2+rxz^2+ryz^2)), LAMBDA=1, MU=0.5
        const float energy = 0.5f * rtr * rtr
                           + 0.5f * (rxx * rxx + ryy * ryy + rzz * rzz
                                     + 2.0f * (rxy * rxy + rxz * rxz + ryz * ryz));

        // NOTE: replicate the reference expression EXACTLY (it is NOT the true
        // determinant — terms 2 and 3 use (1+dw_dx) / (1+dv_dy)*(1+dw_dx)).
        const float jac =
              (1.0f + du_dx) * ((1.0f + dv_dy) * (1.0f + dw_dz) - dv_dz * dw_dy)
            - du_dy * (dv_dx * (1.0f + dw_dz) - dv_dz * (1.0f + dw_dx))
            + du_dz * (dv_dx * dw_dy - (1.0f + dv_dy) * (1.0f + dw_dx));

        vsum += energy + 0.1f * fmaxf(-jac, 0.0f);
    }

    // wave-64 reduction
    #pragma unroll
    for (int off = 32; off > 0; off >>= 1)
        vsum += __shfl_down(vsum, off, 64);

    __shared__ float wpart[4];
    if ((tx & 63) == 0) wpart[tx >> 6] = vsum;
    __syncthreads();
    if (tx == 0) {
        double s = (double)wpart[0] + (double)wpart[1]
                 + (double)wpart[2] + (double)wpart[3];
        unsafeAtomicAdd(acc, s);   // hw global_atomic_add_f64; 2304 total — no contention
    }
}

__global__ void elastic_finalize(const double* __restrict__ acc, float* __restrict__ out) {
    out[0] = (float)(acc[0] * (1.0 / NTOT));
}

extern "C" void kernel_launch(void* const* d_in, const int* in_sizes, int n_in,
                              void* d_out, int out_size, void* d_ws, size_t ws_size,
                              hipStream_t stream) {
    const float* df = (const float*)d_in[0];
    double* acc = (double*)d_ws;
    float* out = (float*)d_out;

    hipMemsetAsync(d_ws, 0, sizeof(double), stream);

    dim3 grid(144, 8, 2);   // 48 j-tiles * 3 k-tiles, 8 i-chunks of 24, 2 batches
    elastic_main<<<grid, 256, 0, stream>>>(df, acc);
    elastic_finalize<<<1, 1, 0, stream>>>(acc, out);
}